// Round 8
// baseline (803.870 us; speedup 1.0000x reference)
//
#include <hip/hip_runtime.h>

#define D 64
#define R 4
#define H_ATT 32
#define SSH 11              // dst-range size shift: S = 2048 nodes
#define SRANGE 2048
#define MAXRANGE 64         // max ranges/relation (N <= 131072)
#define PACK_SH 19          // staged word = (d_local << 19) | src  (N < 524288)
#define QSCALE 4096.0f

typedef __bf16 bf16x4 __attribute__((ext_vector_type(4)));
typedef __bf16 bf16x8 __attribute__((ext_vector_type(8)));
typedef float f32x4 __attribute__((ext_vector_type(4)));
typedef short short4_t __attribute__((ext_vector_type(4)));

// ============ CSR build: single-pass radix partition, per-bucket fill ============

__global__ __launch_bounds__(256) void k_bcount(const int* __restrict__ dst,
                                                int* __restrict__ bcount,
                                                int E, int nrange) {
    __shared__ int cnt[MAXRANGE];
    int r = blockIdx.y;
    const int* dstr = dst + (size_t)r * E;
    for (int i = threadIdx.x; i < nrange; i += 256) cnt[i] = 0;
    __syncthreads();
    int stride = gridDim.x * 256;
    for (int e = blockIdx.x * 256 + threadIdx.x; e < E; e += stride)
        atomicAdd(&cnt[__builtin_nontemporal_load(&dstr[e]) >> SSH], 1);
    __syncthreads();
    for (int i = threadIdx.x; i < nrange; i += 256)
        if (cnt[i]) atomicAdd(&bcount[r * nrange + i], cnt[i]);
}

__global__ void k_bscan(const int* __restrict__ bcount, int* __restrict__ bstart,
                        int* __restrict__ gcur, int nbuck) {
    __shared__ int tmp[257];
    int t = threadIdx.x;
    if (t < nbuck) tmp[t] = bcount[t];
    __syncthreads();
    if (t == 0) {
        int run = 0;
        for (int i = 0; i < nbuck; i++) { int v = tmp[i]; tmp[i] = run; run += v; }
        tmp[nbuck] = run;
    }
    __syncthreads();
    if (t <= nbuck) bstart[t] = tmp[t];
    if (t < nbuck) gcur[t] = tmp[t];
}

__global__ __launch_bounds__(512) void k_part(const int* __restrict__ src,
                                              const int* __restrict__ dst,
                                              int* __restrict__ gcur,
                                              int* __restrict__ staged,
                                              int E, int nrange) {
    __shared__ int cnt[MAXRANGE];
    __shared__ int gbase[MAXRANGE];
    int r = blockIdx.y;
    const int* dstr = dst + (size_t)r * E;
    const int* srcr = src + (size_t)r * E;
    int* gcr = gcur + r * nrange;
    int t = threadIdx.x;
    int nsb = (E + 4095) >> 12;
    for (int sb = blockIdx.x; sb < nsb; sb += gridDim.x) {
        int e0 = sb << 12;
        for (int i = t; i < nrange; i += 512) cnt[i] = 0;
        __syncthreads();
        int pk[8], rk[8], lb[8];
        bool val[8];
        for (int u = 0; u < 8; u++) {
            int e = e0 + u * 512 + t;
            val[u] = e < E;
            if (val[u]) {
                int d = __builtin_nontemporal_load(&dstr[e]);
                int s = __builtin_nontemporal_load(&srcr[e]);
                lb[u] = d >> SSH;
                pk[u] = ((d & (SRANGE - 1)) << PACK_SH) | s;
                rk[u] = atomicAdd(&cnt[lb[u]], 1);
            }
        }
        __syncthreads();
        for (int i = t; i < nrange; i += 512) {
            int c = cnt[i];
            gbase[i] = c ? atomicAdd(&gcr[i], c) : 0;
        }
        __syncthreads();
        for (int u = 0; u < 8; u++) {
            if (val[u])
                __builtin_nontemporal_store(pk[u], &staged[gbase[lb[u]] + rk[u]]);
        }
        __syncthreads();
    }
}

__global__ __launch_bounds__(1024) void k_degb(const int* __restrict__ staged,
                                               const int* __restrict__ bstart,
                                               int* __restrict__ degi,
                                               int N, int nrange) {
    __shared__ int hist[SRANGE];
    int b = blockIdx.x;
    int r = b / nrange, range = b - r * nrange;
    for (int i = threadIdx.x; i < SRANGE; i += 1024) hist[i] = 0;
    __syncthreads();
    int p0 = bstart[b], p1 = bstart[b + 1];
    for (int p = p0 + threadIdx.x; p < p1; p += 1024)
        atomicAdd(&hist[__builtin_nontemporal_load(&staged[p]) >> PACK_SH], 1);
    __syncthreads();
    int base = range << SSH;
    int slen = min(SRANGE, N - base);
    for (int i = threadIdx.x; i < slen; i += 1024)
        degi[r * N + base + i] = hist[i];
}

__global__ __launch_bounds__(1024) void k_fillb(const int* __restrict__ staged,
                                                const int* __restrict__ bstart,
                                                const int* __restrict__ offs,
                                                int* __restrict__ esrc,
                                                int N, int nrange) {
    __shared__ int cur[SRANGE];
    int b = blockIdx.x;
    int r = b / nrange, range = b - r * nrange;
    int base = range << SSH;
    int slen = min(SRANGE, N - base);
    for (int i = threadIdx.x; i < slen; i += 1024)
        cur[i] = offs[r * N + base + i];
    __syncthreads();
    int p0 = bstart[b], p1 = bstart[b + 1];
    for (int p = p0 + threadIdx.x; p < p1; p += 1024) {
        int w = __builtin_nontemporal_load(&staged[p]);
        int dloc = w >> PACK_SH;
        int s = w & ((1 << PACK_SH) - 1);
        int pos = atomicAdd(&cur[dloc], 1);
        esrc[pos] = s;
    }
}

// ============ offs scan (over R*N degrees) ============

__global__ void k_scan_block(const int* __restrict__ in, int* __restrict__ out,
                             int* __restrict__ bsums, int total) {
    int t = threadIdx.x;
    int base = blockIdx.x * 1024;
    int v[4];
    for (int i = 0; i < 4; i++) {
        int idx = base + t * 4 + i;
        v[i] = (idx < total) ? in[idx] : 0;
    }
    int tsum = v[0] + v[1] + v[2] + v[3];
    int lane = t & 63, w = t >> 6;
    int x = tsum;
    for (int o = 1; o < 64; o <<= 1) {
        int y = __shfl_up(x, o);
        if (lane >= o) x += y;
    }
    __shared__ int wsum[4];
    if (lane == 63) wsum[w] = x;
    __syncthreads();
    int wbase = 0;
    for (int i = 0; i < w; i++) wbase += wsum[i];
    int excl = wbase + x - tsum;
    int run = excl;
    for (int i = 0; i < 4; i++) {
        int idx = base + t * 4 + i;
        if (idx < total) out[idx] = run;
        run += v[i];
    }
    if (t == 255) bsums[blockIdx.x] = excl + tsum;
}

__global__ void k_scan_bsums(int* __restrict__ bsums, int nb) {
    __shared__ int tmp[512];
    int t = threadIdx.x;
    for (int i = t; i < nb; i += 256) tmp[i] = bsums[i];
    __syncthreads();
    if (t == 0) {
        int run = 0;
        for (int i = 0; i < nb; i++) { int v = tmp[i]; tmp[i] = run; run += v; }
    }
    __syncthreads();
    for (int i = t; i < nb; i += 256) bsums[i] = tmp[i];
}

__global__ void k_scan_add(int* __restrict__ out, const int* __restrict__ bsums, int total) {
    int idx = blockIdx.x * blockDim.x + threadIdx.x;
    if (idx < total) out[idx] += bsums[idx >> 10];
}

// ============ weight precompute: transposed bf16 hi/lo (once per call) ============
__global__ void k_prep(const float* __restrict__ W1, const float* __restrict__ W2,
                       const float* __restrict__ a1W, const float* __restrict__ a2W,
                       __bf16* __restrict__ WtHi, __bf16* __restrict__ WtLo,
                       __bf16* __restrict__ attWtHi) {
    int idx = blockIdx.x * 256 + threadIdx.x;
    if (idx < 32768) {
        int layer = idx >> 14;
        int rem = idx & 16383;
        int r = rem >> 12;
        int ce = rem & 4095;
        int c = ce >> 6, k = ce & 63;
        const float* W = layer ? W2 : W1;
        float w = W[r * 4096 + k * 64 + c];
        __bf16 hi = (__bf16)w;
        __bf16 lo = (__bf16)(w - (float)hi);
        WtHi[idx] = hi;
        WtLo[idx] = lo;
    } else if (idx < 32768 + 4096) {
        int i2 = idx - 32768;
        int layer = i2 >> 11;
        int rem = i2 & 2047;
        int m = rem >> 6, k = rem & 63;
        const float* aW = layer ? a2W : a1W;
        attWtHi[i2] = (__bf16)(aW[k * H_ATT + m]);
    }
}

// ============ int16 quantization of gather operand ============
__global__ void k_quant(const float* __restrict__ xin, short* __restrict__ xq, int total4) {
    int idx = blockIdx.x * 256 + threadIdx.x;
    if (idx >= total4) return;
    float4 v = reinterpret_cast<const float4*>(xin)[idx];
    short4_t q;
    int a;
    a = (int)rintf(v.x * QSCALE); a = min(max(a, -32767), 32767); q[0] = (short)a;
    a = (int)rintf(v.y * QSCALE); a = min(max(a, -32767), 32767); q[1] = (short)a;
    a = (int)rintf(v.z * QSCALE); a = min(max(a, -32767), 32767); q[2] = (short)a;
    a = (int)rintf(v.w * QSCALE); a = min(max(a, -32767), 32767); q[3] = (short)a;
    reinterpret_cast<short4_t*>(xq)[idx] = q;
}

// ============ per-layer kernels ============

// gather v3: one block per node, wave w = relation w.
// Lane l covers feature pair (2f, 2f+1), f = l&31, for edges of parity g = l>>5.
// One 4B load covers 2 edges across the wave; esrc loaded 64-at-a-time and
// broadcast via __shfl (LDS pipe) -> VMEM queue holds only row loads.
__global__ __launch_bounds__(256) void k_gather(const short* __restrict__ xq,
                                                const int* __restrict__ esrc,
                                                const int* __restrict__ offs,
                                                const int* __restrict__ degi,
                                                float* __restrict__ agg, int N) {
    int n = blockIdx.x;
    int w = threadIdx.x >> 6;
    int l = threadIdx.x & 63;
    unsigned fb = (unsigned)(l & 31) * 4u;   // byte offset of feature pair in row
    int g = l >> 5;
    int idx = w * N + n;
    int eo = offs[idx];
    int cnt = degi[idx];
    const char* xb = (const char*)xq;
    int a0 = 0, a1 = 0;
    for (int b0 = 0; b0 < cnt; b0 += 64) {
        int lim = cnt - b0;
        lim = lim < 64 ? lim : 64;
        int sv = (l < lim) ? esrc[eo + b0 + l] : 0;
        int j = 0;
        for (; j + 16 <= lim; j += 16) {
            int ss[8];
            #pragma unroll
            for (int u = 0; u < 8; u++) ss[u] = __shfl(sv, j + 2 * u + g);
            int vv[8];
            #pragma unroll
            for (int u = 0; u < 8; u++)
                vv[u] = *(const int*)(xb + ((unsigned)ss[u] * 128u + fb));
            #pragma unroll
            for (int u = 0; u < 8; u++) {
                a0 += (int)(short)(vv[u] & 0xffff);
                a1 += (vv[u] >> 16);
            }
        }
        for (; j + 2 <= lim; j += 2) {
            int s = __shfl(sv, j + g);
            int v = *(const int*)(xb + ((unsigned)s * 128u + fb));
            a0 += (int)(short)(v & 0xffff);
            a1 += (v >> 16);
        }
        if (j < lim) {
            int s = __shfl(sv, j);      // uniform shfl before divergence
            if (g == 0) {
                int v = *(const int*)(xb + ((unsigned)s * 128u + fb));
                a0 += (int)(short)(v & 0xffff);
                a1 += (v >> 16);
            }
        }
    }
    a0 += __shfl_xor(a0, 32);
    a1 += __shfl_xor(a1, 32);
    float inv = (1.f / QSCALE) / fmaxf((float)cnt, 1.f);
    agg[((size_t)n * R + w) * D + (l & 31) * 2 + g] = (float)(g ? a1 : a0) * inv;
}

// Fused: h = relu(agg @ W[r] + b[r]) via split-bf16 MFMA; score via bf16 MFMA.
#define OFF_A_HI 0
#define OFF_A_LO 8192
#define OFF_B_HI 16384
#define OFF_B_LO 24576
#define OFF_ATTW 32768
__global__ __launch_bounds__(256) void k_rgemm(
        float* hbuf, const __bf16* __restrict__ WtHi, const __bf16* __restrict__ WtLo,
        const __bf16* __restrict__ attWHi, const float* __restrict__ bias,
        const float* __restrict__ attb, const float* __restrict__ attv,
        float* __restrict__ wspread, int N) {
    __shared__ __align__(16) char L[36864];
    float* hs = (float*)L;
    int t = threadIdx.x;
    int r = blockIdx.y;
    int n0 = blockIdx.x * 64;

    for (int rep = 0; rep < 4; rep++) {
        int row = rep * 16 + (t >> 4);
        int kq = (t & 15) * 4;
        float4 v = {0.f, 0.f, 0.f, 0.f};
        if (n0 + row < N)
            v = *reinterpret_cast<const float4*>(&hbuf[((size_t)(n0 + row) * R + r) * D + kq]);
        bf16x4 hv, lv;
        float f[4] = {v.x, v.y, v.z, v.w};
        for (int j = 0; j < 4; j++) {
            __bf16 h = (__bf16)f[j];
            hv[j] = h;
            lv[j] = (__bf16)(f[j] - (float)h);
        }
        int boff = row * 128 + ((kq * 2) ^ ((row & 7) << 4));
        *reinterpret_cast<bf16x4*>(L + OFF_A_HI + boff) = hv;
        *reinterpret_cast<bf16x4*>(L + OFF_A_LO + boff) = lv;
    }
    {
        const char* gh = (const char*)(WtHi + (size_t)r * 4096);
        const char* gl = (const char*)(WtLo + (size_t)r * 4096);
        for (int rep = 0; rep < 2; rep++) {
            int idx = rep * 256 + t;
            int c = idx >> 3;
            int ko = (idx & 7) * 16;
            int boff = c * 128 + (ko ^ ((c & 7) << 4));
            *reinterpret_cast<uint4*>(L + OFF_B_HI + boff) =
                *reinterpret_cast<const uint4*>(gh + idx * 16);
            *reinterpret_cast<uint4*>(L + OFF_B_LO + boff) =
                *reinterpret_cast<const uint4*>(gl + idx * 16);
        }
        const char* ga = (const char*)attWHi;
        int c = t >> 3;
        int ko = (t & 7) * 16;
        int boff = c * 128 + (ko ^ ((c & 7) << 4));
        *reinterpret_cast<uint4*>(L + OFF_ATTW + boff) =
            *reinterpret_cast<const uint4*>(ga + t * 16);
    }
    __syncthreads();

    int w = t >> 6, l = t & 63;
    int lrow = l & 15, lg = l >> 4;
    int swz = (lrow & 7) << 4;

    f32x4 acc[4] = {{0.f, 0.f, 0.f, 0.f}, {0.f, 0.f, 0.f, 0.f},
                    {0.f, 0.f, 0.f, 0.f}, {0.f, 0.f, 0.f, 0.f}};
    #pragma unroll
    for (int kk = 0; kk < 2; kk++) {
        int koff = (kk * 32 + lg * 8) * 2;
        int aoff = (16 * w + lrow) * 128 + (koff ^ swz);
        bf16x8 ahi = *reinterpret_cast<const bf16x8*>(L + OFF_A_HI + aoff);
        bf16x8 alo = *reinterpret_cast<const bf16x8*>(L + OFF_A_LO + aoff);
        #pragma unroll
        for (int c = 0; c < 4; c++) {
            int boff = (16 * c + lrow) * 128 + (koff ^ swz);
            bf16x8 bhi = *reinterpret_cast<const bf16x8*>(L + OFF_B_HI + boff);
            bf16x8 blo = *reinterpret_cast<const bf16x8*>(L + OFF_B_LO + boff);
            acc[c] = __builtin_amdgcn_mfma_f32_16x16x32_bf16(ahi, bhi, acc[c], 0, 0, 0);
            acc[c] = __builtin_amdgcn_mfma_f32_16x16x32_bf16(ahi, blo, acc[c], 0, 0, 0);
            acc[c] = __builtin_amdgcn_mfma_f32_16x16x32_bf16(alo, bhi, acc[c], 0, 0, 0);
        }
    }
    __syncthreads();

    #pragma unroll
    for (int c = 0; c < 4; c++) {
        int col = 16 * c + lrow;
        float bv = bias[r * D + col];
        #pragma unroll
        for (int reg = 0; reg < 4; reg++) {
            int row = 16 * w + lg * 4 + reg;
            hs[row * 68 + col] = fmaxf(acc[c][reg] + bv, 0.f);
        }
    }
    __syncthreads();

    for (int jj = 0; jj < 4; jj++) {
        int idx = jj * 256 + t;
        int row = idx >> 4;
        int sg = (idx & 15) * 4;
        if (n0 + row < N) {
            float4 v = *reinterpret_cast<const float4*>(&hs[row * 68 + sg]);
            *reinterpret_cast<float4*>(&hbuf[((size_t)(n0 + row) * R + r) * D + sg]) = v;
        }
    }

    f32x4 sacc[2] = {{0.f, 0.f, 0.f, 0.f}, {0.f, 0.f, 0.f, 0.f}};
    #pragma unroll
    for (int kk = 0; kk < 2; kk++) {
        int hrow = 16 * w + lrow;
        const float* hp = hs + hrow * 68 + kk * 32 + lg * 8;
        float4 f0 = *reinterpret_cast<const float4*>(hp);
        float4 f1 = *reinterpret_cast<const float4*>(hp + 4);
        bf16x8 ha;
        ha[0] = (__bf16)f0.x; ha[1] = (__bf16)f0.y; ha[2] = (__bf16)f0.z; ha[3] = (__bf16)f0.w;
        ha[4] = (__bf16)f1.x; ha[5] = (__bf16)f1.y; ha[6] = (__bf16)f1.z; ha[7] = (__bf16)f1.w;
        int koff = (kk * 32 + lg * 8) * 2;
        #pragma unroll
        for (int c = 0; c < 2; c++) {
            int boff = (16 * c + lrow) * 128 + (koff ^ swz);
            bf16x8 bw = *reinterpret_cast<const bf16x8*>(L + OFF_ATTW + boff);
            sacc[c] = __builtin_amdgcn_mfma_f32_16x16x32_bf16(ha, bw, sacc[c], 0, 0, 0);
        }
    }
    float tot = 0.f;
    #pragma unroll
    for (int c = 0; c < 2; c++) {
        int m = 16 * c + lrow;
        float ab = attb[m], av = attv[m];
        #pragma unroll
        for (int reg = 0; reg < 4; reg++) {
            int node = n0 + 16 * w + lg * 4 + reg;
            float tv = tanhf(sacc[c][reg] + ab) * av;
            tot += (node < N) ? tv : 0.f;
        }
    }
    for (int o = 1; o < 64; o <<= 1) tot += __shfl_xor(tot, o);
    if (l == 0) atomicAdd(&wspread[r * 1024 + (blockIdx.x & 1023)], tot);
}

__global__ void k_beta(const float* __restrict__ wspread, float* __restrict__ beta, int N) {
    __shared__ float sums[4];
    int wid = threadIdx.x >> 6, lane = threadIdx.x & 63;
    float s = 0.f;
    for (int i = lane; i < 1024; i += 64) s += wspread[wid * 1024 + i];
    for (int o = 32; o > 0; o >>= 1) s += __shfl_down(s, o);
    if (lane == 0) sums[wid] = s;
    __syncthreads();
    if (threadIdx.x == 0) {
        float mean[R], m = -1e30f;
        for (int r = 0; r < R; r++) { mean[r] = sums[r] / (float)N; m = fmaxf(m, mean[r]); }
        float e[R], tot = 0.f;
        for (int r = 0; r < R; r++) { e[r] = expf(mean[r] - m); tot += e[r]; }
        for (int r = 0; r < R; r++) beta[r] = e[r] / tot;
    }
}

// combine + (optional) fused int16 quantization of the output for next layer
__global__ void k_combine(const float* __restrict__ h, const float* __restrict__ beta,
                          float* __restrict__ out, short* __restrict__ xq, int doq, int N) {
    int idx = blockIdx.x * blockDim.x + threadIdx.x;
    int n = idx >> 4, q = idx & 15;
    if (n >= N) return;
    float b0 = beta[0], b1 = beta[1], b2 = beta[2], b3 = beta[3];
    const float4* hp = reinterpret_cast<const float4*>(&h[(size_t)n * R * D]);
    float4 v0 = hp[q], v1 = hp[16 + q], v2 = hp[32 + q], v3 = hp[48 + q];
    float4 o;
    o.x = b0 * v0.x + b1 * v1.x + b2 * v2.x + b3 * v3.x;
    o.y = b0 * v0.y + b1 * v1.y + b2 * v2.y + b3 * v3.y;
    o.z = b0 * v0.z + b1 * v1.z + b2 * v2.z + b3 * v3.z;
    o.w = b0 * v0.w + b1 * v1.w + b2 * v2.w + b3 * v3.w;
    reinterpret_cast<float4*>(out)[idx] = o;
    if (doq) {
        short4_t qv;
        int a;
        a = (int)rintf(o.x * QSCALE); a = min(max(a, -32767), 32767); qv[0] = (short)a;
        a = (int)rintf(o.y * QSCALE); a = min(max(a, -32767), 32767); qv[1] = (short)a;
        a = (int)rintf(o.z * QSCALE); a = min(max(a, -32767), 32767); qv[2] = (short)a;
        a = (int)rintf(o.w * QSCALE); a = min(max(a, -32767), 32767); qv[3] = (short)a;
        reinterpret_cast<short4_t*>(xq)[idx] = qv;
    }
}

extern "C" void kernel_launch(void* const* d_in, const int* in_sizes, int n_in,
                              void* d_out, int out_size, void* d_ws, size_t ws_size,
                              hipStream_t stream) {
    const float* x   = (const float*)d_in[0];
    const int*   src = (const int*)d_in[1];
    const int*   dst = (const int*)d_in[2];
    const float* W1  = (const float*)d_in[3];
    const float* b1  = (const float*)d_in[4];
    const float* a1W = (const float*)d_in[5];
    const float* a1b = (const float*)d_in[6];
    const float* a1v = (const float*)d_in[7];
    const float* W2  = (const float*)d_in[8];
    const float* b2  = (const float*)d_in[9];
    const float* a2W = (const float*)d_in[10];
    const float* a2b = (const float*)d_in[11];
    const float* a2v = (const float*)d_in[12];

    int N = in_sizes[0] / D;
    int E = in_sizes[1] / R;
    int RN = R * N;
    int nrange = (N + SRANGE - 1) >> SSH;   // 49 for N=100000
    int nbuck = R * nrange;                 // 196
    float* out = (float*)d_out;

    char* ws = (char*)d_ws;
    float* agg     = (float*)ws; ws += (size_t)N * R * D * 4;
    int*   degi    = (int*)ws;   ws += (size_t)RN * 4;
    int*   offs    = (int*)ws;   ws += (size_t)RN * 4;
    int*   esrc    = (int*)ws;   ws += (size_t)R * E * 4;
    int*   staged  = (int*)ws;   ws += (size_t)R * E * 4;
    short* xq      = (short*)ws; ws += (size_t)N * D * 2;
    int*   bcount  = (int*)ws;   ws += 1024;
    int*   bstart  = (int*)ws;   ws += 1040;
    int*   gcur    = (int*)ws;   ws += 1024;
    int*   bsums   = (int*)ws;   ws += 4096;
    float* wspread = (float*)ws; ws += (size_t)R * 1024 * 4;
    float* beta    = (float*)ws; ws += 64;
    __bf16* WtHi   = (__bf16*)ws; ws += 2 * R * 4096 * 2;
    __bf16* WtLo   = (__bf16*)ws; ws += 2 * R * 4096 * 2;
    __bf16* attWHi = (__bf16*)ws; ws += 2 * 2048 * 2;

    // ---- weight precompute + input quantization ----
    k_prep<<<144, 256, 0, stream>>>(W1, W2, a1W, a2W, WtHi, WtLo, attWHi);
    int total4 = N * D / 4;
    k_quant<<<(total4 + 255) / 256, 256, 0, stream>>>(x, xq, total4);

    // ---- CSR build: radix partition + per-bucket count/fill ----
    hipMemsetAsync(bcount, 0, (size_t)nbuck * 4, stream);
    k_bcount<<<dim3(128, R), 256, 0, stream>>>(dst, bcount, E, nrange);
    k_bscan<<<1, 256, 0, stream>>>(bcount, bstart, gcur, nbuck);
    k_part<<<dim3(128, R), 512, 0, stream>>>(src, dst, gcur, staged, E, nrange);
    k_degb<<<nbuck, 1024, 0, stream>>>(staged, bstart, degi, N, nrange);
    int nb1024 = (RN + 1023) / 1024;
    k_scan_block<<<nb1024, 256, 0, stream>>>(degi, offs, bsums, RN);
    k_scan_bsums<<<1, 256, 0, stream>>>(bsums, nb1024);
    k_scan_add<<<(RN + 255) / 256, 256, 0, stream>>>(offs, bsums, RN);
    k_fillb<<<nbuck, 1024, 0, stream>>>(staged, bstart, offs, esrc, N, nrange);

    int nbg = (N + 63) / 64;
    for (int layer = 0; layer < 2; layer++) {
        const float* bb = layer ? b2 : b1;
        const float* ab = layer ? a2b : a1b;
        const float* av = layer ? a2v : a1v;
        const __bf16* wh = WtHi + (size_t)layer * 16384;
        const __bf16* wl = WtLo + (size_t)layer * 16384;
        const __bf16* aw = attWHi + (size_t)layer * 2048;

        hipMemsetAsync(wspread, 0, (size_t)R * 1024 * 4, stream);
        k_gather<<<N, 256, 0, stream>>>(xq, esrc, offs, degi, agg, N);
        k_rgemm<<<dim3(nbg, R), 256, 0, stream>>>(agg, wh, wl, aw, bb, ab, av, wspread, N);
        k_beta<<<1, 256, 0, stream>>>(wspread, beta, N);
        k_combine<<<(N * 16 + 255) / 256, 256, 0, stream>>>(agg, beta, out, xq,
                                                            layer == 0 ? 1 : 0, N);
    }
}

// Round 9
// 725.092 us; speedup vs baseline: 1.1086x; 1.1086x over previous
//
#include <hip/hip_runtime.h>

#define D 64
#define R 4
#define H_ATT 32
#define SSH 11              // dst-range size shift: S = 2048 nodes
#define SRANGE 2048
#define MAXRANGE 64         // max ranges/relation (N <= 131072)
#define PACK_SH 19          // staged word = (d_local << 19) | src  (N < 524288)
#define QSCALE 4096.0f

typedef __bf16 bf16x4 __attribute__((ext_vector_type(4)));
typedef __bf16 bf16x8 __attribute__((ext_vector_type(8)));
typedef float f32x4 __attribute__((ext_vector_type(4)));
typedef short short4_t __attribute__((ext_vector_type(4)));
typedef short short8_t __attribute__((ext_vector_type(8)));

// ============ CSR build: single-pass radix partition, per-bucket fill ============

__global__ __launch_bounds__(256) void k_bcount(const int* __restrict__ dst,
                                                int* __restrict__ bcount,
                                                int E, int nrange) {
    __shared__ int cnt[4][MAXRANGE];
    int r = blockIdx.y;
    const int* dstr = dst + (size_t)r * E;
    int wid = threadIdx.x >> 6;
    for (int i = threadIdx.x; i < 4 * MAXRANGE; i += 256) cnt[i >> 6][i & 63] = 0;
    __syncthreads();
    int stride = gridDim.x * 256;
    for (int e = blockIdx.x * 256 + threadIdx.x; e < E; e += stride)
        atomicAdd(&cnt[wid][__builtin_nontemporal_load(&dstr[e]) >> SSH], 1);
    __syncthreads();
    for (int i = threadIdx.x; i < nrange; i += 256) {
        int tot = cnt[0][i] + cnt[1][i] + cnt[2][i] + cnt[3][i];
        if (tot) atomicAdd(&bcount[r * nrange + i], tot);
    }
}

__global__ void k_bscan(const int* __restrict__ bcount, int* __restrict__ bstart,
                        int* __restrict__ gcur, int nbuck) {
    __shared__ int tmp[257];
    int t = threadIdx.x;
    if (t < nbuck) tmp[t] = bcount[t];
    __syncthreads();
    if (t == 0) {
        int run = 0;
        for (int i = 0; i < nbuck; i++) { int v = tmp[i]; tmp[i] = run; run += v; }
        tmp[nbuck] = run;
    }
    __syncthreads();
    if (t <= nbuck) bstart[t] = tmp[t];
    if (t < nbuck) gcur[t] = tmp[t];
}

__global__ __launch_bounds__(512) void k_part(const int* __restrict__ src,
                                              const int* __restrict__ dst,
                                              int* __restrict__ gcur,
                                              int* __restrict__ staged,
                                              int E, int nrange) {
    __shared__ int cnt[MAXRANGE];
    __shared__ int gbase[MAXRANGE];
    int r = blockIdx.y;
    const int* dstr = dst + (size_t)r * E;
    const int* srcr = src + (size_t)r * E;
    int* gcr = gcur + r * nrange;
    int t = threadIdx.x;
    int nsb = (E + 4095) >> 12;
    for (int sb = blockIdx.x; sb < nsb; sb += gridDim.x) {
        int e0 = sb << 12;
        for (int i = t; i < nrange; i += 512) cnt[i] = 0;
        __syncthreads();
        int pk[8], rk[8], lb[8];
        bool val[8];
        for (int u = 0; u < 8; u++) {
            int e = e0 + u * 512 + t;
            val[u] = e < E;
            if (val[u]) {
                int d = __builtin_nontemporal_load(&dstr[e]);
                int s = __builtin_nontemporal_load(&srcr[e]);
                lb[u] = d >> SSH;
                pk[u] = ((d & (SRANGE - 1)) << PACK_SH) | s;
                rk[u] = atomicAdd(&cnt[lb[u]], 1);
            }
        }
        __syncthreads();
        for (int i = t; i < nrange; i += 512) {
            int c = cnt[i];
            gbase[i] = c ? atomicAdd(&gcr[i], c) : 0;
        }
        __syncthreads();
        for (int u = 0; u < 8; u++) {
            if (val[u])
                __builtin_nontemporal_store(pk[u], &staged[gbase[lb[u]] + rk[u]]);
        }
        __syncthreads();
    }
}

// Fused per-bucket: LDS degree hist -> block scan -> offs/degi -> cursor fill.
// Replaces k_degb + global offs scan chain + k_fillb.
__global__ __launch_bounds__(1024) void k_csr2(const int* __restrict__ staged,
                                               const int* __restrict__ bstart,
                                               int* __restrict__ offs,
                                               int* __restrict__ degi,
                                               int* __restrict__ esrc,
                                               int N, int nrange) {
    __shared__ int hist[SRANGE];
    __shared__ int wp[16];
    int b = blockIdx.x;
    int r = b / nrange, range = b - r * nrange;
    int base = range << SSH;
    int slen = min(SRANGE, N - base);
    int t = threadIdx.x;
    for (int i = t; i < SRANGE; i += 1024) hist[i] = 0;
    __syncthreads();
    int p0 = bstart[b], p1 = bstart[b + 1];
    for (int p = p0 + t; p < p1; p += 1024)
        atomicAdd(&hist[(unsigned)staged[p] >> PACK_SH], 1);
    __syncthreads();
    // block exclusive scan of hist (each thread owns 2 consecutive entries)
    int a0 = hist[2 * t], a1 = hist[2 * t + 1];
    int s = a0 + a1;
    int lane = t & 63, wid = t >> 6;
    int x = s;
    for (int o = 1; o < 64; o <<= 1) {
        int y = __shfl_up(x, o);
        if (lane >= o) x += y;
    }
    if (lane == 63) wp[wid] = x;
    __syncthreads();   // all hist reads done; wp ready
    if (t == 0) {
        int run = 0;
        for (int i = 0; i < 16; i++) { int v = wp[i]; wp[i] = run; run += v; }
    }
    __syncthreads();
    int ex = wp[wid] + (x - s);
    hist[2 * t] = ex;
    hist[2 * t + 1] = ex + a0;
    if (2 * t < slen) {
        offs[r * N + base + 2 * t] = p0 + ex;
        degi[r * N + base + 2 * t] = a0;
    }
    if (2 * t + 1 < slen) {
        offs[r * N + base + 2 * t + 1] = p0 + ex + a0;
        degi[r * N + base + 2 * t + 1] = a1;
    }
    __syncthreads();   // hist now = bucket-local cursors
    for (int p = p0 + t; p < p1; p += 1024) {
        int w = staged[p];
        int dloc = (unsigned)w >> PACK_SH;
        int pos = p0 + atomicAdd(&hist[dloc], 1);
        esrc[pos] = w & ((1 << PACK_SH) - 1);
    }
}

// ============ weight precompute: transposed bf16 hi/lo (once per call) ============
__global__ void k_prep(const float* __restrict__ W1, const float* __restrict__ W2,
                       const float* __restrict__ a1W, const float* __restrict__ a2W,
                       __bf16* __restrict__ WtHi, __bf16* __restrict__ WtLo,
                       __bf16* __restrict__ attWtHi) {
    int idx = blockIdx.x * 256 + threadIdx.x;
    if (idx < 32768) {
        int layer = idx >> 14;
        int rem = idx & 16383;
        int r = rem >> 12;
        int ce = rem & 4095;
        int c = ce >> 6, k = ce & 63;
        const float* W = layer ? W2 : W1;
        float w = W[r * 4096 + k * 64 + c];
        __bf16 hi = (__bf16)w;
        __bf16 lo = (__bf16)(w - (float)hi);
        WtHi[idx] = hi;
        WtLo[idx] = lo;
    } else if (idx < 32768 + 4096) {
        int i2 = idx - 32768;
        int layer = i2 >> 11;
        int rem = i2 & 2047;
        int m = rem >> 6, k = rem & 63;
        const float* aW = layer ? a2W : a1W;
        attWtHi[i2] = (__bf16)(aW[k * H_ATT + m]);
    }
}

// ============ int16 quantization of gather operand ============
__global__ void k_quant(const float* __restrict__ xin, short* __restrict__ xq, int total4) {
    int idx = blockIdx.x * 256 + threadIdx.x;
    if (idx >= total4) return;
    float4 v = reinterpret_cast<const float4*>(xin)[idx];
    short4_t q;
    int a;
    a = (int)rintf(v.x * QSCALE); a = min(max(a, -32767), 32767); q[0] = (short)a;
    a = (int)rintf(v.y * QSCALE); a = min(max(a, -32767), 32767); q[1] = (short)a;
    a = (int)rintf(v.z * QSCALE); a = min(max(a, -32767), 32767); q[2] = (short)a;
    a = (int)rintf(v.w * QSCALE); a = min(max(a, -32767), 32767); q[3] = (short)a;
    reinterpret_cast<short4_t*>(xq)[idx] = q;
}

// ============ per-layer kernels ============

// gather: one block per node, wave w = relation w; int16 rows, exact int32 accum,
// int16 agg output (value = mean in QSCALE units, rounded).
__global__ __launch_bounds__(256) void k_gather(const short* __restrict__ xq,
                                                const int* __restrict__ esrc,
                                                const int* __restrict__ offs,
                                                const int* __restrict__ degi,
                                                short* __restrict__ aggq, int N) {
    int n = blockIdx.x;
    int w = threadIdx.x >> 6;
    int l = threadIdx.x & 63;
    unsigned fb = (unsigned)(l & 31) * 4u;
    int g = l >> 5;
    int idx = w * N + n;
    int eo = offs[idx];
    int cnt = degi[idx];
    const char* xb = (const char*)xq;
    int a0 = 0, a1 = 0;
    for (int b0 = 0; b0 < cnt; b0 += 64) {
        int lim = cnt - b0;
        lim = lim < 64 ? lim : 64;
        int sv = (l < lim) ? esrc[eo + b0 + l] : 0;
        int j = 0;
        for (; j + 16 <= lim; j += 16) {
            int ss[8];
            #pragma unroll
            for (int u = 0; u < 8; u++) ss[u] = __shfl(sv, j + 2 * u + g);
            int vv[8];
            #pragma unroll
            for (int u = 0; u < 8; u++)
                vv[u] = *(const int*)(xb + ((unsigned)ss[u] * 128u + fb));
            #pragma unroll
            for (int u = 0; u < 8; u++) {
                a0 += (int)(short)(vv[u] & 0xffff);
                a1 += (vv[u] >> 16);
            }
        }
        for (; j + 2 <= lim; j += 2) {
            int s = __shfl(sv, j + g);
            int v = *(const int*)(xb + ((unsigned)s * 128u + fb));
            a0 += (int)(short)(v & 0xffff);
            a1 += (v >> 16);
        }
        if (j < lim) {
            int s = __shfl(sv, j);
            if (g == 0) {
                int v = *(const int*)(xb + ((unsigned)s * 128u + fb));
                a0 += (int)(short)(v & 0xffff);
                a1 += (v >> 16);
            }
        }
    }
    a0 += __shfl_xor(a0, 32);
    a1 += __shfl_xor(a1, 32);
    float inv = 1.f / fmaxf((float)cnt, 1.f);
    int q = (int)rintf((float)(g ? a1 : a0) * inv);
    aggq[((size_t)n * R + w) * D + (l & 31) * 2 + g] = (short)q;
}

// Fused: h = relu(agg @ W[r] + b[r]) via split-bf16 MFMA; score via bf16 MFMA.
// agg/h are int16 in QSCALE units; in-place (block reads its rows before writing).
#define OFF_A_HI 0
#define OFF_A_LO 8192
#define OFF_B_HI 16384
#define OFF_B_LO 24576
#define OFF_ATTW 32768
__global__ __launch_bounds__(256) void k_rgemm(
        short* hbuf, const __bf16* __restrict__ WtHi, const __bf16* __restrict__ WtLo,
        const __bf16* __restrict__ attWHi, const float* __restrict__ bias,
        const float* __restrict__ attb, const float* __restrict__ attv,
        float* __restrict__ wspread, int N) {
    __shared__ __align__(16) char L[36864];
    float* hs = (float*)L;
    int t = threadIdx.x;
    int r = blockIdx.y;
    int n0 = blockIdx.x * 64;
    const float IQ = 1.f / QSCALE;

    for (int rep = 0; rep < 4; rep++) {
        int row = rep * 16 + (t >> 4);
        int kq = (t & 15) * 4;
        short4_t qv = {0, 0, 0, 0};
        if (n0 + row < N)
            qv = *reinterpret_cast<const short4_t*>(&hbuf[((size_t)(n0 + row) * R + r) * D + kq]);
        bf16x4 hv, lv;
        for (int j = 0; j < 4; j++) {
            float f = (float)qv[j] * IQ;
            __bf16 h = (__bf16)f;
            hv[j] = h;
            lv[j] = (__bf16)(f - (float)h);
        }
        int boff = row * 128 + ((kq * 2) ^ ((row & 7) << 4));
        *reinterpret_cast<bf16x4*>(L + OFF_A_HI + boff) = hv;
        *reinterpret_cast<bf16x4*>(L + OFF_A_LO + boff) = lv;
    }
    {
        const char* gh = (const char*)(WtHi + (size_t)r * 4096);
        const char* gl = (const char*)(WtLo + (size_t)r * 4096);
        for (int rep = 0; rep < 2; rep++) {
            int idx = rep * 256 + t;
            int c = idx >> 3;
            int ko = (idx & 7) * 16;
            int boff = c * 128 + (ko ^ ((c & 7) << 4));
            *reinterpret_cast<uint4*>(L + OFF_B_HI + boff) =
                *reinterpret_cast<const uint4*>(gh + idx * 16);
            *reinterpret_cast<uint4*>(L + OFF_B_LO + boff) =
                *reinterpret_cast<const uint4*>(gl + idx * 16);
        }
        const char* ga = (const char*)attWHi;
        int c = t >> 3;
        int ko = (t & 7) * 16;
        int boff = c * 128 + (ko ^ ((c & 7) << 4));
        *reinterpret_cast<uint4*>(L + OFF_ATTW + boff) =
            *reinterpret_cast<const uint4*>(ga + t * 16);
    }
    __syncthreads();

    int w = t >> 6, l = t & 63;
    int lrow = l & 15, lg = l >> 4;
    int swz = (lrow & 7) << 4;

    f32x4 acc[4] = {{0.f, 0.f, 0.f, 0.f}, {0.f, 0.f, 0.f, 0.f},
                    {0.f, 0.f, 0.f, 0.f}, {0.f, 0.f, 0.f, 0.f}};
    #pragma unroll
    for (int kk = 0; kk < 2; kk++) {
        int koff = (kk * 32 + lg * 8) * 2;
        int aoff = (16 * w + lrow) * 128 + (koff ^ swz);
        bf16x8 ahi = *reinterpret_cast<const bf16x8*>(L + OFF_A_HI + aoff);
        bf16x8 alo = *reinterpret_cast<const bf16x8*>(L + OFF_A_LO + aoff);
        #pragma unroll
        for (int c = 0; c < 4; c++) {
            int boff = (16 * c + lrow) * 128 + (koff ^ swz);
            bf16x8 bhi = *reinterpret_cast<const bf16x8*>(L + OFF_B_HI + boff);
            bf16x8 blo = *reinterpret_cast<const bf16x8*>(L + OFF_B_LO + boff);
            acc[c] = __builtin_amdgcn_mfma_f32_16x16x32_bf16(ahi, bhi, acc[c], 0, 0, 0);
            acc[c] = __builtin_amdgcn_mfma_f32_16x16x32_bf16(ahi, blo, acc[c], 0, 0, 0);
            acc[c] = __builtin_amdgcn_mfma_f32_16x16x32_bf16(alo, bhi, acc[c], 0, 0, 0);
        }
    }
    __syncthreads();

    #pragma unroll
    for (int c = 0; c < 4; c++) {
        int col = 16 * c + lrow;
        float bv = bias[r * D + col];
        #pragma unroll
        for (int reg = 0; reg < 4; reg++) {
            int row = 16 * w + lg * 4 + reg;
            hs[row * 68 + col] = fmaxf(acc[c][reg] + bv, 0.f);
        }
    }
    __syncthreads();

    // coalesced global store of h as int16 (QSCALE units)
    for (int jj = 0; jj < 4; jj++) {
        int idx = jj * 256 + t;
        int row = idx >> 4;
        int sg = (idx & 15) * 4;
        if (n0 + row < N) {
            float4 v = *reinterpret_cast<const float4*>(&hs[row * 68 + sg]);
            short4_t qv;
            float f;
            f = fminf(fmaxf(v.x * QSCALE, -32767.f), 32767.f); qv[0] = (short)(int)rintf(f);
            f = fminf(fmaxf(v.y * QSCALE, -32767.f), 32767.f); qv[1] = (short)(int)rintf(f);
            f = fminf(fmaxf(v.z * QSCALE, -32767.f), 32767.f); qv[2] = (short)(int)rintf(f);
            f = fminf(fmaxf(v.w * QSCALE, -32767.f), 32767.f); qv[3] = (short)(int)rintf(f);
            *reinterpret_cast<short4_t*>(&hbuf[((size_t)(n0 + row) * R + r) * D + sg]) = qv;
        }
    }

    f32x4 sacc[2] = {{0.f, 0.f, 0.f, 0.f}, {0.f, 0.f, 0.f, 0.f}};
    #pragma unroll
    for (int kk = 0; kk < 2; kk++) {
        int hrow = 16 * w + lrow;
        const float* hp = hs + hrow * 68 + kk * 32 + lg * 8;
        float4 f0 = *reinterpret_cast<const float4*>(hp);
        float4 f1 = *reinterpret_cast<const float4*>(hp + 4);
        bf16x8 ha;
        ha[0] = (__bf16)f0.x; ha[1] = (__bf16)f0.y; ha[2] = (__bf16)f0.z; ha[3] = (__bf16)f0.w;
        ha[4] = (__bf16)f1.x; ha[5] = (__bf16)f1.y; ha[6] = (__bf16)f1.z; ha[7] = (__bf16)f1.w;
        int koff = (kk * 32 + lg * 8) * 2;
        #pragma unroll
        for (int c = 0; c < 2; c++) {
            int boff = (16 * c + lrow) * 128 + (koff ^ swz);
            bf16x8 bw = *reinterpret_cast<const bf16x8*>(L + OFF_ATTW + boff);
            sacc[c] = __builtin_amdgcn_mfma_f32_16x16x32_bf16(ha, bw, sacc[c], 0, 0, 0);
        }
    }
    float tot = 0.f;
    #pragma unroll
    for (int c = 0; c < 2; c++) {
        int m = 16 * c + lrow;
        float ab = attb[m], av = attv[m];
        #pragma unroll
        for (int reg = 0; reg < 4; reg++) {
            int node = n0 + 16 * w + lg * 4 + reg;
            float tv = tanhf(sacc[c][reg] + ab) * av;
            tot += (node < N) ? tv : 0.f;
        }
    }
    for (int o = 1; o < 64; o <<= 1) tot += __shfl_xor(tot, o);
    if (l == 0) atomicAdd(&wspread[r * 1024 + (blockIdx.x & 1023)], tot);
}

__global__ void k_beta(const float* __restrict__ wspread, float* __restrict__ beta, int N) {
    __shared__ float sums[4];
    int wid = threadIdx.x >> 6, lane = threadIdx.x & 63;
    float s = 0.f;
    for (int i = lane; i < 1024; i += 64) s += wspread[wid * 1024 + i];
    for (int o = 32; o > 0; o >>= 1) s += __shfl_down(s, o);
    if (lane == 0) sums[wid] = s;
    __syncthreads();
    if (threadIdx.x == 0) {
        float mean[R], m = -1e30f;
        for (int r = 0; r < R; r++) { mean[r] = sums[r] / (float)N; m = fmaxf(m, mean[r]); }
        float e[R], tot = 0.f;
        for (int r = 0; r < R; r++) { e[r] = expf(mean[r] - m); tot += e[r]; }
        for (int r = 0; r < R; r++) beta[r] = e[r] / tot;
    }
}

// combine over int16 h: out fp32; optional fused int16 re-quant for next layer
__global__ void k_combine(const short* __restrict__ hq, const float* __restrict__ beta,
                          float* __restrict__ out, short* __restrict__ xq, int doq, int N) {
    int idx = blockIdx.x * blockDim.x + threadIdx.x;
    int n = idx >> 3, q = idx & 7;
    if (n >= N) return;
    float b0 = beta[0] * (1.f / QSCALE), b1 = beta[1] * (1.f / QSCALE);
    float b2 = beta[2] * (1.f / QSCALE), b3 = beta[3] * (1.f / QSCALE);
    const short8_t* hp = reinterpret_cast<const short8_t*>(&hq[(size_t)n * R * D]);
    short8_t v0 = hp[q], v1 = hp[8 + q], v2 = hp[16 + q], v3 = hp[24 + q];
    float o[8];
    #pragma unroll
    for (int j = 0; j < 8; j++)
        o[j] = b0 * (float)v0[j] + b1 * (float)v1[j] + b2 * (float)v2[j] + b3 * (float)v3[j];
    float4 oa = {o[0], o[1], o[2], o[3]};
    float4 ob = {o[4], o[5], o[6], o[7]};
    float4* op = reinterpret_cast<float4*>(&out[(size_t)n * D + q * 8]);
    op[0] = oa;
    op[1] = ob;
    if (doq) {
        short8_t qv;
        #pragma unroll
        for (int j = 0; j < 8; j++) {
            float f = fminf(fmaxf(o[j] * QSCALE, -32767.f), 32767.f);
            qv[j] = (short)(int)rintf(f);
        }
        reinterpret_cast<short8_t*>(&xq[(size_t)n * D + q * 8])[0] = qv;
    }
}

extern "C" void kernel_launch(void* const* d_in, const int* in_sizes, int n_in,
                              void* d_out, int out_size, void* d_ws, size_t ws_size,
                              hipStream_t stream) {
    const float* x   = (const float*)d_in[0];
    const int*   src = (const int*)d_in[1];
    const int*   dst = (const int*)d_in[2];
    const float* W1  = (const float*)d_in[3];
    const float* b1  = (const float*)d_in[4];
    const float* a1W = (const float*)d_in[5];
    const float* a1b = (const float*)d_in[6];
    const float* a1v = (const float*)d_in[7];
    const float* W2  = (const float*)d_in[8];
    const float* b2  = (const float*)d_in[9];
    const float* a2W = (const float*)d_in[10];
    const float* a2b = (const float*)d_in[11];
    const float* a2v = (const float*)d_in[12];

    int N = in_sizes[0] / D;
    int E = in_sizes[1] / R;
    int RN = R * N;
    int nrange = (N + SRANGE - 1) >> SSH;   // 49 for N=100000
    int nbuck = R * nrange;                 // 196
    float* out = (float*)d_out;

    char* ws = (char*)d_ws;
    short* aggq    = (short*)ws; ws += (size_t)N * R * D * 2;   // agg/h int16, in-place
    int*   degi    = (int*)ws;   ws += (size_t)RN * 4;
    int*   offs    = (int*)ws;   ws += (size_t)RN * 4;
    int*   esrc    = (int*)ws;   ws += (size_t)R * E * 4;
    int*   staged  = (int*)ws;   ws += (size_t)R * E * 4;
    short* xq      = (short*)ws; ws += (size_t)N * D * 2;
    int*   bcount  = (int*)ws;   ws += 1024;
    int*   bstart  = (int*)ws;   ws += 1040;
    int*   gcur    = (int*)ws;   ws += 1024;
    float* wspread = (float*)ws; ws += (size_t)R * 1024 * 4;
    float* beta    = (float*)ws; ws += 64;
    __bf16* WtHi   = (__bf16*)ws; ws += 2 * R * 4096 * 2;
    __bf16* WtLo   = (__bf16*)ws; ws += 2 * R * 4096 * 2;
    __bf16* attWHi = (__bf16*)ws; ws += 2 * 2048 * 2;

    // ---- weight precompute + input quantization ----
    k_prep<<<144, 256, 0, stream>>>(W1, W2, a1W, a2W, WtHi, WtLo, attWHi);
    int total4 = N * D / 4;
    k_quant<<<(total4 + 255) / 256, 256, 0, stream>>>(x, xq, total4);

    // ---- CSR build: radix partition + fused per-bucket hist/scan/fill ----
    hipMemsetAsync(bcount, 0, (size_t)nbuck * 4, stream);
    k_bcount<<<dim3(128, R), 256, 0, stream>>>(dst, bcount, E, nrange);
    k_bscan<<<1, 256, 0, stream>>>(bcount, bstart, gcur, nbuck);
    k_part<<<dim3(128, R), 512, 0, stream>>>(src, dst, gcur, staged, E, nrange);
    k_csr2<<<nbuck, 1024, 0, stream>>>(staged, bstart, offs, degi, esrc, N, nrange);

    int nbg = (N + 63) / 64;
    for (int layer = 0; layer < 2; layer++) {
        const float* bb = layer ? b2 : b1;
        const float* ab = layer ? a2b : a1b;
        const float* av = layer ? a2v : a1v;
        const __bf16* wh = WtHi + (size_t)layer * 16384;
        const __bf16* wl = WtLo + (size_t)layer * 16384;
        const __bf16* aw = attWHi + (size_t)layer * 2048;

        hipMemsetAsync(wspread, 0, (size_t)R * 1024 * 4, stream);
        k_gather<<<N, 256, 0, stream>>>(xq, esrc, offs, degi, aggq, N);
        k_rgemm<<<dim3(nbg, R), 256, 0, stream>>>(aggq, wh, wl, aw, bb, ab, av, wspread, N);
        k_beta<<<1, 256, 0, stream>>>(wspread, beta, N);
        k_combine<<<(N * 8 + 255) / 256, 256, 0, stream>>>(aggq, beta, out, xq,
                                                           layer == 0 ? 1 : 0, N);
    }
}